// Round 7
// baseline (312.795 us; speedup 1.0000x reference)
//
#include <hip/hip_runtime.h>

using short8  = __attribute__((ext_vector_type(8))) short;
using floatx4 = __attribute__((ext_vector_type(4))) float;

#define NB   8192
#define DIN  256
#define DE   128
#define NEX  16384
#define ND   64
#define ESPLIT 32
#define EPB  (NEX/ESPLIT)   // 512 exemplars per block
#define TE   64
#define NTIL (EPB/TE)       // 8 tiles
#define GAMMA_N 3.6787944117144233e-06f  // exp(-1)/100000

__device__ __forceinline__ unsigned short f2bf(float f) {
  unsigned int u = __float_as_uint(f);
  u += 0x7fffu + ((u >> 16) & 1u);
  return (unsigned short)(u >> 16);
}
__device__ __forceinline__ float bf2f(unsigned short h) {
  return __uint_as_float(((unsigned int)h) << 16);
}
__device__ __forceinline__ unsigned int pk_bf16(float a, float b) {
  unsigned int r;
  asm("v_cvt_pk_bf16_f32 %0, %1, %2" : "=v"(r) : "v"(a), "v"(b));
  return r;
}

__device__ __forceinline__ void gload_lds16(const void* g, void* l) {
  __builtin_amdgcn_global_load_lds(
      (const __attribute__((address_space(1))) void*)g,
      (__attribute__((address_space(3))) void*)l, 16, 0, 0);
}

__device__ __forceinline__ floatx4 mfma_bf16(short8 a, short8 b, floatx4 c) {
  return __builtin_amdgcn_mfma_f32_16x16x32_bf16(a, b, c, 0, 0, 0);
}

// ---------------- encoder: phi = x@W + b (4x4 register tile) --------------
__global__ __launch_bounds__(256) void k_encoder(
    const float* __restrict__ x, const float* __restrict__ W,
    const float* __restrict__ bias, unsigned short* __restrict__ phi_bf,
    float* __restrict__ pn)
{
  __shared__ float xs[32 * DIN];      // 32 KB
  const int rb  = blockIdx.x * 32;
  const int tid = threadIdx.x;
  for (int i = tid; i < 32 * DIN / 4; i += 256)
    reinterpret_cast<float4*>(xs)[i] =
        reinterpret_cast<const float4*>(x + (size_t)rb * DIN)[i];
  __syncthreads();
  const int jt = tid & 31;            // col group: j = jt*4
  const int rt = tid >> 5;            // row group: r = rt*4
  const float4 bj = *reinterpret_cast<const float4*>(&bias[jt * 4]);
  float4 a0 = bj, a1 = bj, a2 = bj, a3 = bj;
  const float* xr = xs + rt * 4 * DIN;
  #pragma unroll 4
  for (int k = 0; k < DIN; ++k) {
    const float4 wv = *reinterpret_cast<const float4*>(&W[k * DE + jt * 4]);
    const float x0 = xr[k], x1 = xr[DIN + k], x2 = xr[2 * DIN + k], x3 = xr[3 * DIN + k];
    a0.x = fmaf(x0, wv.x, a0.x); a0.y = fmaf(x0, wv.y, a0.y);
    a0.z = fmaf(x0, wv.z, a0.z); a0.w = fmaf(x0, wv.w, a0.w);
    a1.x = fmaf(x1, wv.x, a1.x); a1.y = fmaf(x1, wv.y, a1.y);
    a1.z = fmaf(x1, wv.z, a1.z); a1.w = fmaf(x1, wv.w, a1.w);
    a2.x = fmaf(x2, wv.x, a2.x); a2.y = fmaf(x2, wv.y, a2.y);
    a2.z = fmaf(x2, wv.z, a2.z); a2.w = fmaf(x2, wv.w, a2.w);
    a3.x = fmaf(x3, wv.x, a3.x); a3.y = fmaf(x3, wv.y, a3.y);
    a3.z = fmaf(x3, wv.z, a3.z); a3.w = fmaf(x3, wv.w, a3.w);
  }
  float4 av[4] = {a0, a1, a2, a3};
  #pragma unroll
  for (int rr = 0; rr < 4; ++rr) {
    const int row = rb + rt * 4 + rr;
    const unsigned int p0 = pk_bf16(av[rr].x, av[rr].y);
    const unsigned int p1 = pk_bf16(av[rr].z, av[rr].w);
    *reinterpret_cast<uint2*>(phi_bf + (size_t)row * DE + jt * 4) =
        make_uint2(p0, p1);
    const float h0 = bf2f(p0 & 0xffff), h1 = bf2f(p0 >> 16);
    const float h2 = bf2f(p1 & 0xffff), h3 = bf2f(p1 >> 16);
    float s = h0 * h0 + h1 * h1 + h2 * h2 + h3 * h3;
    s += __shfl_xor(s, 1, 64);
    s += __shfl_xor(s, 2, 64);
    s += __shfl_xor(s, 4, 64);
    s += __shfl_xor(s, 8, 64);
    s += __shfl_xor(s, 16, 64);   // stays within the 32-lane jt group
    if (jt == 0) pn[row] = s;
  }
}

// ---------------- exemplar prep: bf16 copy + |E_bf|^2 (vectorized) --------
__global__ __launch_bounds__(256) void k_prep_e(
    const float* __restrict__ E, unsigned short* __restrict__ E_bf,
    float* __restrict__ en)
{
  const int tid = threadIdx.x;
  const int w = tid >> 6, l = tid & 63;
  const int row = blockIdx.x * 32 + w * 8 + (l >> 3);
  const int c0  = (l & 7) * 16;
  const float4* src = reinterpret_cast<const float4*>(E + (size_t)row * DE + c0);
  float4 v0 = src[0], v1 = src[1], v2 = src[2], v3 = src[3];
  unsigned int p[8];
  p[0] = pk_bf16(v0.x, v0.y); p[1] = pk_bf16(v0.z, v0.w);
  p[2] = pk_bf16(v1.x, v1.y); p[3] = pk_bf16(v1.z, v1.w);
  p[4] = pk_bf16(v2.x, v2.y); p[5] = pk_bf16(v2.z, v2.w);
  p[6] = pk_bf16(v3.x, v3.y); p[7] = pk_bf16(v3.z, v3.w);
  uint4* dst = reinterpret_cast<uint4*>(E_bf + (size_t)row * DE + c0);
  dst[0] = make_uint4(p[0], p[1], p[2], p[3]);
  dst[1] = make_uint4(p[4], p[5], p[6], p[7]);
  float s = 0.f;
  #pragma unroll
  for (int i = 0; i < 8; ++i) {
    const float lo = bf2f(p[i] & 0xffff), hi = bf2f(p[i] >> 16);
    s = fmaf(lo, lo, s); s = fmaf(hi, hi, s);
  }
  s += __shfl_xor(s, 1, 64);
  s += __shfl_xor(s, 2, 64);
  s += __shfl_xor(s, 4, 64);
  if ((l & 7) == 0) en[row] = s;
}

// ---------------- KM curves -> transposed KM_t[t][e] bf16 -----------------
__global__ __launch_bounds__(256) void k_prep_km(
    const float* __restrict__ lev, const float* __restrict__ lcen,
    const float* __restrict__ lh, unsigned short* __restrict__ KM_t,
    float* __restrict__ baseKM)
{
  __shared__ unsigned short sm[64][65];
  const int tid = threadIdx.x;
  const int t   = tid & 63;
  const int wv  = tid >> 6;
  for (int ee = 0; ee < 16; ++ee) {
    const int el = wv * 16 + ee;
    const int e  = blockIdx.x * 64 + el;
    const float ev = __expf(lev[e * ND + t]);
    const float cn = __expf(lcen[e * ND + t]);
    float s = ev + cn;
    #pragma unroll
    for (int off = 1; off < 64; off <<= 1) {         // inclusive suffix sum
      const float o = __shfl(s, (t + off) & 63, 64);
      s += (t + off < 64) ? o : 0.0f;
    }
    const float haz = (s > 0.0f) ? (ev / s) : 0.0f;
    float lc = __logf(1.0f - haz + 1e-7f);
    #pragma unroll
    for (int off = 1; off < 64; off <<= 1) {         // inclusive prefix sum
      const float o = __shfl(lc, (t - off) & 63, 64);
      lc += (t >= off) ? o : 0.0f;
    }
    sm[el][t] = f2bf(__expf(lc));
  }
  __syncthreads();
  const int t_out = tid >> 2, prt = tid & 3;
  unsigned short tmp[16];
  #pragma unroll
  for (int i = 0; i < 16; ++i) tmp[i] = sm[prt * 16 + i][t_out];
  *reinterpret_cast<short8*>(KM_t + (size_t)t_out * NEX + blockIdx.x * 64 + prt * 16) =
      *reinterpret_cast<short8*>(&tmp[0]);
  *reinterpret_cast<short8*>(KM_t + (size_t)t_out * NEX + blockIdx.x * 64 + prt * 16 + 8) =
      *reinterpret_cast<short8*>(&tmp[8]);
  if (blockIdx.x == 0 && tid < 64) {
    const float h = 1.0f / (1.0f + __expf(-lh[t]));
    float l2 = __logf(1.0f - h + 1e-7f);
    #pragma unroll
    for (int off = 1; off < 64; off <<= 1) {
      const float o = __shfl(l2, (t - off) & 63, 64);
      l2 += (t >= off) ? o : 0.0f;
    }
    baseKM[t] = __expf(l2);
  }
}

// ---------------- fused (swapped operands, half-tile kw, 32 KB LDS) -------
// GEMM1': C1[e][r] = E . phi^T  -> kw (bf16) to 64B-row LDS, per 32-e half
// GEMM2': C2[t][r] = KM^T . kw^T -> regs; epilogue = wave-CONTIGUOUS bf16
// partial stores (512B per store instruction -> full lines, no RFO).
__global__ __launch_bounds__(256, 5) void k_fused(
    const unsigned short* __restrict__ phi_bf, const float* __restrict__ pn,
    const unsigned short* __restrict__ E_bf, const float* __restrict__ en,
    const unsigned short* __restrict__ KM_t,
    uint2* __restrict__ numer_p, float* __restrict__ denom_p)
{
  __shared__ __align__(16) unsigned char E_lds[16384];   // [64 e][256B], swizzled
  __shared__ __align__(16) unsigned char KM_lds[8192];   // [64 t][128B], swizzled
  __shared__ __align__(16) unsigned char kw_lds[8192];   // per-wave [32 r][64B], swizzled

  const int tid = threadIdx.x;
  const int w   = tid >> 6;
  const int l   = tid & 63;
  const int lr  = l & 15;
  const int g   = l >> 4;
  const int rowbase = blockIdx.y * 128 + w * 32;
  const int ebase0  = blockIdx.x * EPB;
  const int swz  = (lr & 7) << 4;          // bits 4-6, for 128/256B rows
  const int swz2 = ((lr >> 1) & 3) << 4;   // bits 4-5, for 64B kw rows (b128-safe)

  // persistent B-fragments: phi rows (cols of C), loaded once
  short8 phiB[2][4];
  float  pnf[2];
  #pragma unroll
  for (int n = 0; n < 2; ++n) {
    const int r = rowbase + n * 16 + lr;
    #pragma unroll
    for (int kq = 0; kq < 4; ++kq)
      phiB[n][kq] = *reinterpret_cast<const short8*>(phi_bf + r * DE + kq * 32 + g * 8);
    pnf[n] = pn[r];
  }

  floatx4 c2[4][2];
  #pragma unroll
  for (int m2 = 0; m2 < 4; ++m2)
    #pragma unroll
    for (int n = 0; n < 2; ++n) c2[m2][n] = (floatx4){0.f, 0.f, 0.f, 0.f};
  float dn[2] = {0.f, 0.f};

  for (int it = 0; it < NTIL; ++it) {
    const int ebase = ebase0 + it * TE;
    __syncthreads();                   // prev tile's LDS readers done
    // stage E tile: 16 x 1KB chunks, linear LDS dest, pre-swizzled source
    #pragma unroll
    for (int i = 0; i < 4; ++i) {
      const int c    = w * 4 + i;
      const int row  = c * 4 + (l >> 4);
      const int colB = (l & 15) * 16;
      gload_lds16((const char*)E_bf + (size_t)(ebase + row) * 256 +
                      (colB ^ ((row & 7) << 4)),
                  &E_lds[c * 1024]);
    }
    // stage KM tile: 8 x 1KB chunks from transposed KM_t
    #pragma unroll
    for (int i = 0; i < 2; ++i) {
      const int c    = w * 2 + i;
      const int trow = c * 8 + (l >> 3);
      const int colB = (l & 7) * 16;
      gload_lds16((const char*)KM_t + (size_t)trow * (NEX * 2) + ebase * 2 +
                      (colB ^ ((trow & 7) << 4)),
                  &KM_lds[c * 1024]);
    }
    __syncthreads();

    #pragma unroll
    for (int h = 0; h < 2; ++h) {
      // GEMM1' on this 32-exemplar half + kw pack to LDS
      #pragma unroll
      for (int mm = 0; mm < 2; ++mm) {
        const int m = 2 * h + mm;
        short8 ea[4];
        #pragma unroll
        for (int kq = 0; kq < 4; ++kq)
          ea[kq] = *reinterpret_cast<const short8*>(
              &E_lds[(m * 16 + lr) * 256 + ((kq * 64 + g * 16) ^ swz)]);
        floatx4 c1[2];
        c1[0] = (floatx4){0.f, 0.f, 0.f, 0.f};
        c1[1] = (floatx4){0.f, 0.f, 0.f, 0.f};
        #pragma unroll
        for (int kq = 0; kq < 4; ++kq) {
          c1[0] = mfma_bf16(ea[kq], phiB[0][kq], c1[0]);
          c1[1] = mfma_bf16(ea[kq], phiB[1][kq], c1[1]);
        }
        const floatx4 en4 = *reinterpret_cast<const floatx4*>(&en[ebase + m * 16 + g * 4]);
        #pragma unroll
        for (int n = 0; n < 2; ++n) {
          float kwv[4];
          #pragma unroll
          for (int rg = 0; rg < 4; ++rg) {
            const float d2 = en4[rg] + pnf[n] - 2.0f * c1[n][rg];
            kwv[rg] = (d2 <= 1.0f) ? __expf(-d2) : 0.0f;
            dn[n] += kwv[rg];
          }
          const unsigned int pk0 = pk_bf16(kwv[0], kwv[1]);
          const unsigned int pk1 = pk_bf16(kwv[2], kwv[3]);
          const unsigned long long pk = (unsigned long long)pk0 |
                                        ((unsigned long long)pk1 << 32);
          *reinterpret_cast<unsigned long long*>(
              &kw_lds[w * 2048 + (n * 16 + lr) * 64 + ((mm * 32 + g * 8) ^ swz2)]) = pk;
        }
      }
      // GEMM2' on this half (same-wave LDS RAW, no barrier)
      short8 kwB[2];
      #pragma unroll
      for (int n = 0; n < 2; ++n)
        kwB[n] = *reinterpret_cast<const short8*>(
            &kw_lds[w * 2048 + (n * 16 + lr) * 64 + ((g * 16) ^ swz2)]);
      #pragma unroll
      for (int m2 = 0; m2 < 4; ++m2) {
        const short8 kma = *reinterpret_cast<const short8*>(
            &KM_lds[(m2 * 16 + lr) * 128 + ((h * 64 + g * 16) ^ swz)]);
        c2[m2][0] = mfma_bf16(kma, kwB[0], c2[m2][0]);
        c2[m2][1] = mfma_bf16(kma, kwB[1], c2[m2][1]);
      }
    }
  }

  // epilogue: denom f32 + numer bf16 wave-contiguous stores (full lines)
  #pragma unroll
  for (int n = 0; n < 2; ++n) {
    float v = dn[n];
    v += __shfl_xor(v, 16, 64);
    v += __shfl_xor(v, 32, 64);
    if (l < 16) denom_p[(size_t)blockIdx.x * NB + rowbase + n * 16 + lr] = v;
  }
  // layout: [blk = y*ESPLIT+x][w][n*4+m2][lane] of uint2 (4 bf16 each)
  uint2* np = numer_p +
      ((size_t)(blockIdx.y * ESPLIT + blockIdx.x) * 4 + w) * 512;
  #pragma unroll
  for (int n = 0; n < 2; ++n)
    #pragma unroll
    for (int m2 = 0; m2 < 4; ++m2)
      np[(n * 4 + m2) * 64 + l] =
          make_uint2(pk_bf16(c2[m2][n][0], c2[m2][n][1]),
                     pk_bf16(c2[m2][n][2], c2[m2][n][3]));
}

// ---------------- finalize: reduce ESPLIT bf16 partials + clip ------------
__global__ __launch_bounds__(256) void k_finalize(
    const unsigned short* __restrict__ numer_p, const float* __restrict__ denom_p,
    const float* __restrict__ baseKM, float* __restrict__ out)
{
  const int idx = blockIdx.x * 256 + threadIdx.x;
  const int b = idx >> 6;
  const int t = idx & 63;
  // inverse of k_fused's store layout
  const int y  = b >> 7, w = (b >> 5) & 3, n = (b >> 4) & 1, lr = b & 15;
  const int m2 = t >> 4, g = (t >> 2) & 3, rg = t & 3;
  const size_t base = (size_t)y * ESPLIT * 8192 + w * 2048 +
                      (n * 4 + m2) * 256 + (g * 16 + lr) * 4 + rg;
  float num = 0.f, den = 0.f;
  #pragma unroll
  for (int s = 0; s < ESPLIT; ++s) {
    num += bf2f(numer_p[base + (size_t)s * 8192]);
    den += denom_p[(size_t)s * NB + b];
  }
  num += GAMMA_N * baseKM[t];
  den += GAMMA_N + 1e-12f;
  float r = num / den;
  r = fminf(fmaxf(r, 1e-12f), 1.0f - 1e-12f);
  out[idx] = r;
}

extern "C" void kernel_launch(void* const* d_in, const int* in_sizes, int n_in,
                              void* d_out, int out_size, void* d_ws, size_t ws_size,
                              hipStream_t stream)
{
  const float* x    = (const float*)d_in[0];
  const float* W    = (const float*)d_in[1];
  const float* bias = (const float*)d_in[2];
  const float* E    = (const float*)d_in[3];
  const float* lev  = (const float*)d_in[4];
  const float* lcen = (const float*)d_in[5];
  const float* lh   = (const float*)d_in[6];
  float* out = (float*)d_out;

  char* ws = (char*)d_ws;
  size_t off = 0;
  auto alloc = [&](size_t bytes) -> void* {
    void* p = ws + off;
    off += (bytes + 255) & ~(size_t)255;
    return p;
  };
  unsigned short* phi_bf  = (unsigned short*)alloc((size_t)NB * DE * 2);
  unsigned short* E_bf    = (unsigned short*)alloc((size_t)NEX * DE * 2);
  unsigned short* KM_t    = (unsigned short*)alloc((size_t)ND * NEX * 2);
  float* pn       = (float*)alloc((size_t)NB * 4);
  float* en       = (float*)alloc((size_t)NEX * 4);
  float* baseKM   = (float*)alloc((size_t)ND * 4);
  uint2* numer_p  = (uint2*)alloc((size_t)ESPLIT * NB * ND * 2);   // 33.5 MB
  float* denom_p  = (float*)alloc((size_t)ESPLIT * NB * 4);        // 1 MB

  k_encoder<<<NB / 32, 256, 0, stream>>>(x, W, bias, phi_bf, pn);
  k_prep_e<<<NEX / 32, 256, 0, stream>>>(E, E_bf, en);
  k_prep_km<<<NEX / 64, 256, 0, stream>>>(lev, lcen, lh, KM_t, baseKM);
  k_fused<<<dim3(ESPLIT, NB / 128), 256, 0, stream>>>(phi_bf, pn, E_bf, en, KM_t,
                                                      numer_p, denom_p);
  k_finalize<<<(NB * ND) / 256, 256, 0, stream>>>((const unsigned short*)numer_p,
                                                  denom_p, baseKM, out);
}

// Round 8
// 197.263 us; speedup vs baseline: 1.5857x; 1.5857x over previous
//
#include <hip/hip_runtime.h>

using short8  = __attribute__((ext_vector_type(8))) short;
using floatx4 = __attribute__((ext_vector_type(4))) float;

#define NB   8192
#define DIN  256
#define DE   128
#define NEX  16384
#define ND   64
#define ESPLIT 16
#define EPB  (NEX/ESPLIT)   // 1024 exemplars per block
#define TE   64
#define NTIL (EPB/TE)       // 16 tiles
#define GAMMA_N 3.6787944117144233e-06f  // exp(-1)/100000

__device__ __forceinline__ unsigned short f2bf(float f) {
  unsigned int u = __float_as_uint(f);
  u += 0x7fffu + ((u >> 16) & 1u);
  return (unsigned short)(u >> 16);
}
__device__ __forceinline__ float bf2f(unsigned short h) {
  return __uint_as_float(((unsigned int)h) << 16);
}
__device__ __forceinline__ unsigned int pk_bf16(float a, float b) {
  unsigned int r;
  asm("v_cvt_pk_bf16_f32 %0, %1, %2" : "=v"(r) : "v"(a), "v"(b));
  return r;
}

__device__ __forceinline__ void gload_lds16(const void* g, void* l) {
  __builtin_amdgcn_global_load_lds(
      (const __attribute__((address_space(1))) void*)g,
      (__attribute__((address_space(3))) void*)l, 16, 0, 0);
}

__device__ __forceinline__ floatx4 mfma_bf16(short8 a, short8 b, floatx4 c) {
  return __builtin_amdgcn_mfma_f32_16x16x32_bf16(a, b, c, 0, 0, 0);
}

// ---------------- encoder: phi = x@W + b (4x4 register tile) --------------
__global__ __launch_bounds__(256) void k_encoder(
    const float* __restrict__ x, const float* __restrict__ W,
    const float* __restrict__ bias, unsigned short* __restrict__ phi_bf,
    float* __restrict__ pn)
{
  __shared__ float xs[32 * DIN];      // 32 KB
  const int rb  = blockIdx.x * 32;
  const int tid = threadIdx.x;
  for (int i = tid; i < 32 * DIN / 4; i += 256)
    reinterpret_cast<float4*>(xs)[i] =
        reinterpret_cast<const float4*>(x + (size_t)rb * DIN)[i];
  __syncthreads();
  const int jt = tid & 31;            // col group: j = jt*4
  const int rt = tid >> 5;            // row group: r = rt*4
  const float4 bj = *reinterpret_cast<const float4*>(&bias[jt * 4]);
  float4 a0 = bj, a1 = bj, a2 = bj, a3 = bj;
  const float* xr = xs + rt * 4 * DIN;
  #pragma unroll 4
  for (int k = 0; k < DIN; ++k) {
    const float4 wv = *reinterpret_cast<const float4*>(&W[k * DE + jt * 4]);
    const float x0 = xr[k], x1 = xr[DIN + k], x2 = xr[2 * DIN + k], x3 = xr[3 * DIN + k];
    a0.x = fmaf(x0, wv.x, a0.x); a0.y = fmaf(x0, wv.y, a0.y);
    a0.z = fmaf(x0, wv.z, a0.z); a0.w = fmaf(x0, wv.w, a0.w);
    a1.x = fmaf(x1, wv.x, a1.x); a1.y = fmaf(x1, wv.y, a1.y);
    a1.z = fmaf(x1, wv.z, a1.z); a1.w = fmaf(x1, wv.w, a1.w);
    a2.x = fmaf(x2, wv.x, a2.x); a2.y = fmaf(x2, wv.y, a2.y);
    a2.z = fmaf(x2, wv.z, a2.z); a2.w = fmaf(x2, wv.w, a2.w);
    a3.x = fmaf(x3, wv.x, a3.x); a3.y = fmaf(x3, wv.y, a3.y);
    a3.z = fmaf(x3, wv.z, a3.z); a3.w = fmaf(x3, wv.w, a3.w);
  }
  float4 av[4] = {a0, a1, a2, a3};
  #pragma unroll
  for (int rr = 0; rr < 4; ++rr) {
    const int row = rb + rt * 4 + rr;
    const unsigned int p0 = pk_bf16(av[rr].x, av[rr].y);
    const unsigned int p1 = pk_bf16(av[rr].z, av[rr].w);
    *reinterpret_cast<uint2*>(phi_bf + (size_t)row * DE + jt * 4) =
        make_uint2(p0, p1);
    const float h0 = bf2f(p0 & 0xffff), h1 = bf2f(p0 >> 16);
    const float h2 = bf2f(p1 & 0xffff), h3 = bf2f(p1 >> 16);
    float s = h0 * h0 + h1 * h1 + h2 * h2 + h3 * h3;
    s += __shfl_xor(s, 1, 64);
    s += __shfl_xor(s, 2, 64);
    s += __shfl_xor(s, 4, 64);
    s += __shfl_xor(s, 8, 64);
    s += __shfl_xor(s, 16, 64);   // stays within the 32-lane jt group
    if (jt == 0) pn[row] = s;
  }
}

// ---------------- exemplar prep: bf16 copy + |E_bf|^2 (vectorized) --------
__global__ __launch_bounds__(256) void k_prep_e(
    const float* __restrict__ E, unsigned short* __restrict__ E_bf,
    float* __restrict__ en)
{
  const int tid = threadIdx.x;
  const int w = tid >> 6, l = tid & 63;
  const int row = blockIdx.x * 32 + w * 8 + (l >> 3);
  const int c0  = (l & 7) * 16;
  const float4* src = reinterpret_cast<const float4*>(E + (size_t)row * DE + c0);
  float4 v0 = src[0], v1 = src[1], v2 = src[2], v3 = src[3];
  unsigned int p[8];
  p[0] = pk_bf16(v0.x, v0.y); p[1] = pk_bf16(v0.z, v0.w);
  p[2] = pk_bf16(v1.x, v1.y); p[3] = pk_bf16(v1.z, v1.w);
  p[4] = pk_bf16(v2.x, v2.y); p[5] = pk_bf16(v2.z, v2.w);
  p[6] = pk_bf16(v3.x, v3.y); p[7] = pk_bf16(v3.z, v3.w);
  uint4* dst = reinterpret_cast<uint4*>(E_bf + (size_t)row * DE + c0);
  dst[0] = make_uint4(p[0], p[1], p[2], p[3]);
  dst[1] = make_uint4(p[4], p[5], p[6], p[7]);
  float s = 0.f;
  #pragma unroll
  for (int i = 0; i < 8; ++i) {
    const float lo = bf2f(p[i] & 0xffff), hi = bf2f(p[i] >> 16);
    s = fmaf(lo, lo, s); s = fmaf(hi, hi, s);
  }
  s += __shfl_xor(s, 1, 64);
  s += __shfl_xor(s, 2, 64);
  s += __shfl_xor(s, 4, 64);
  if ((l & 7) == 0) en[row] = s;
}

// ---------------- KM curves -> transposed KM_t[t][e] bf16 -----------------
__global__ __launch_bounds__(256) void k_prep_km(
    const float* __restrict__ lev, const float* __restrict__ lcen,
    const float* __restrict__ lh, unsigned short* __restrict__ KM_t,
    float* __restrict__ baseKM)
{
  __shared__ unsigned short sm[64][65];
  const int tid = threadIdx.x;
  const int t   = tid & 63;
  const int wv  = tid >> 6;
  for (int ee = 0; ee < 16; ++ee) {
    const int el = wv * 16 + ee;
    const int e  = blockIdx.x * 64 + el;
    const float ev = __expf(lev[e * ND + t]);
    const float cn = __expf(lcen[e * ND + t]);
    float s = ev + cn;
    #pragma unroll
    for (int off = 1; off < 64; off <<= 1) {         // inclusive suffix sum
      const float o = __shfl(s, (t + off) & 63, 64);
      s += (t + off < 64) ? o : 0.0f;
    }
    const float haz = (s > 0.0f) ? (ev / s) : 0.0f;
    float lc = __logf(1.0f - haz + 1e-7f);
    #pragma unroll
    for (int off = 1; off < 64; off <<= 1) {         // inclusive prefix sum
      const float o = __shfl(lc, (t - off) & 63, 64);
      lc += (t >= off) ? o : 0.0f;
    }
    sm[el][t] = f2bf(__expf(lc));
  }
  __syncthreads();
  const int t_out = tid >> 2, prt = tid & 3;
  unsigned short tmp[16];
  #pragma unroll
  for (int i = 0; i < 16; ++i) tmp[i] = sm[prt * 16 + i][t_out];
  *reinterpret_cast<short8*>(KM_t + (size_t)t_out * NEX + blockIdx.x * 64 + prt * 16) =
      *reinterpret_cast<short8*>(&tmp[0]);
  *reinterpret_cast<short8*>(KM_t + (size_t)t_out * NEX + blockIdx.x * 64 + prt * 16 + 8) =
      *reinterpret_cast<short8*>(&tmp[8]);
  if (blockIdx.x == 0 && tid < 64) {
    const float h = 1.0f / (1.0f + __expf(-lh[t]));
    float l2 = __logf(1.0f - h + 1e-7f);
    #pragma unroll
    for (int off = 1; off < 64; off <<= 1) {
      const float o = __shfl(l2, (t - off) & 63, 64);
      l2 += (t >= off) ? o : 0.0f;
    }
    baseKM[t] = __expf(l2);
  }
}

// ---------------- fused (swapped operands, half-tile kw, 32 KB LDS) -------
// GEMM1': C1[e][r] = E . phi^T  -> kw (bf16) to 64B-row LDS, per 32-e half
// GEMM2': C2[t][r] = KM^T . kw^T -> regs; epilogue = f32 floatx4 partials
// (full-line wave stores; coalesced finalize reads).
// launch_bounds (256,4): (256,5) forced VGPR 48 + scratch spills -> 500 MB
// of FETCH/WRITE and 2x slowdown (rounds 6/7). Do not re-tighten.
__global__ __launch_bounds__(256, 4) void k_fused(
    const unsigned short* __restrict__ phi_bf, const float* __restrict__ pn,
    const unsigned short* __restrict__ E_bf, const float* __restrict__ en,
    const unsigned short* __restrict__ KM_t,
    float* __restrict__ numer_p, float* __restrict__ denom_p)
{
  __shared__ __align__(16) unsigned char E_lds[16384];   // [64 e][256B], swizzled
  __shared__ __align__(16) unsigned char KM_lds[8192];   // [64 t][128B], swizzled
  __shared__ __align__(16) unsigned char kw_lds[8192];   // per-wave [32 r][64B], swizzled

  const int tid = threadIdx.x;
  const int w   = tid >> 6;
  const int l   = tid & 63;
  const int lr  = l & 15;
  const int g   = l >> 4;
  const int rowbase = blockIdx.y * 128 + w * 32;
  const int ebase0  = blockIdx.x * EPB;
  const int swz  = (lr & 7) << 4;          // bits 4-6, for 128/256B rows
  const int swz2 = ((lr >> 1) & 3) << 4;   // bits 4-5, for 64B kw rows (b128-safe)

  // persistent B-fragments: phi rows (cols of C), loaded once
  short8 phiB[2][4];
  float  pnf[2];
  #pragma unroll
  for (int n = 0; n < 2; ++n) {
    const int r = rowbase + n * 16 + lr;
    #pragma unroll
    for (int kq = 0; kq < 4; ++kq)
      phiB[n][kq] = *reinterpret_cast<const short8*>(phi_bf + r * DE + kq * 32 + g * 8);
    pnf[n] = pn[r];
  }

  floatx4 c2[4][2];
  #pragma unroll
  for (int m2 = 0; m2 < 4; ++m2)
    #pragma unroll
    for (int n = 0; n < 2; ++n) c2[m2][n] = (floatx4){0.f, 0.f, 0.f, 0.f};
  float dn[2] = {0.f, 0.f};

  for (int it = 0; it < NTIL; ++it) {
    const int ebase = ebase0 + it * TE;
    __syncthreads();                   // prev tile's LDS readers done
    // stage E tile: 16 x 1KB chunks, linear LDS dest, pre-swizzled source
    #pragma unroll
    for (int i = 0; i < 4; ++i) {
      const int c    = w * 4 + i;
      const int row  = c * 4 + (l >> 4);
      const int colB = (l & 15) * 16;
      gload_lds16((const char*)E_bf + (size_t)(ebase + row) * 256 +
                      (colB ^ ((row & 7) << 4)),
                  &E_lds[c * 1024]);
    }
    // stage KM tile: 8 x 1KB chunks from transposed KM_t
    #pragma unroll
    for (int i = 0; i < 2; ++i) {
      const int c    = w * 2 + i;
      const int trow = c * 8 + (l >> 3);
      const int colB = (l & 7) * 16;
      gload_lds16((const char*)KM_t + (size_t)trow * (NEX * 2) + ebase * 2 +
                      (colB ^ ((trow & 7) << 4)),
                  &KM_lds[c * 1024]);
    }
    __syncthreads();

    #pragma unroll
    for (int h = 0; h < 2; ++h) {
      // GEMM1' on this 32-exemplar half + kw pack to LDS
      #pragma unroll
      for (int mm = 0; mm < 2; ++mm) {
        const int m = 2 * h + mm;
        short8 ea[4];
        #pragma unroll
        for (int kq = 0; kq < 4; ++kq)
          ea[kq] = *reinterpret_cast<const short8*>(
              &E_lds[(m * 16 + lr) * 256 + ((kq * 64 + g * 16) ^ swz)]);
        floatx4 c1[2];
        c1[0] = (floatx4){0.f, 0.f, 0.f, 0.f};
        c1[1] = (floatx4){0.f, 0.f, 0.f, 0.f};
        #pragma unroll
        for (int kq = 0; kq < 4; ++kq) {
          c1[0] = mfma_bf16(ea[kq], phiB[0][kq], c1[0]);
          c1[1] = mfma_bf16(ea[kq], phiB[1][kq], c1[1]);
        }
        const floatx4 en4 = *reinterpret_cast<const floatx4*>(&en[ebase + m * 16 + g * 4]);
        #pragma unroll
        for (int n = 0; n < 2; ++n) {
          float kwv[4];
          #pragma unroll
          for (int rg = 0; rg < 4; ++rg) {
            const float d2 = en4[rg] + pnf[n] - 2.0f * c1[n][rg];
            kwv[rg] = (d2 <= 1.0f) ? __expf(-d2) : 0.0f;
            dn[n] += kwv[rg];
          }
          const unsigned int pk0 = pk_bf16(kwv[0], kwv[1]);
          const unsigned int pk1 = pk_bf16(kwv[2], kwv[3]);
          const unsigned long long pk = (unsigned long long)pk0 |
                                        ((unsigned long long)pk1 << 32);
          *reinterpret_cast<unsigned long long*>(
              &kw_lds[w * 2048 + (n * 16 + lr) * 64 + ((mm * 32 + g * 8) ^ swz2)]) = pk;
        }
      }
      // GEMM2' on this half (same-wave LDS RAW, no barrier)
      short8 kwB[2];
      #pragma unroll
      for (int n = 0; n < 2; ++n)
        kwB[n] = *reinterpret_cast<const short8*>(
            &kw_lds[w * 2048 + (n * 16 + lr) * 64 + ((g * 16) ^ swz2)]);
      #pragma unroll
      for (int m2 = 0; m2 < 4; ++m2) {
        const short8 kma = *reinterpret_cast<const short8*>(
            &KM_lds[(m2 * 16 + lr) * 128 + ((h * 64 + g * 16) ^ swz)]);
        c2[m2][0] = mfma_bf16(kma, kwB[0], c2[m2][0]);
        c2[m2][1] = mfma_bf16(kma, kwB[1], c2[m2][1]);
      }
    }
  }

  // epilogue: denom f32 + numer f32 floatx4 stores (full lines, r5-proven)
  #pragma unroll
  for (int n = 0; n < 2; ++n) {
    float v = dn[n];
    v += __shfl_xor(v, 16, 64);
    v += __shfl_xor(v, 32, 64);
    if (l < 16) denom_p[(size_t)blockIdx.x * NB + rowbase + n * 16 + lr] = v;
  }
  float* np = numer_p + ((size_t)blockIdx.x * NB + rowbase) * ND;
  #pragma unroll
  for (int n = 0; n < 2; ++n)
    #pragma unroll
    for (int m2 = 0; m2 < 4; ++m2)
      *reinterpret_cast<floatx4*>(&np[(n * 16 + lr) * ND + m2 * 16 + g * 4]) =
          c2[m2][n];
}

// ---------------- finalize: reduce ESPLIT partials + clip -----------------
__global__ __launch_bounds__(256) void k_finalize(
    const float* __restrict__ numer_p, const float* __restrict__ denom_p,
    const float* __restrict__ baseKM, float* __restrict__ out)
{
  const int idx = blockIdx.x * 256 + threadIdx.x;
  const int b = idx >> 6;
  const int t = idx & 63;
  float num = 0.f, den = 0.f;
  #pragma unroll
  for (int s = 0; s < ESPLIT; ++s) {
    num += numer_p[(size_t)s * NB * ND + idx];
    den += denom_p[(size_t)s * NB + b];
  }
  num += GAMMA_N * baseKM[t];
  den += GAMMA_N + 1e-12f;
  float r = num / den;
  r = fminf(fmaxf(r, 1e-12f), 1.0f - 1e-12f);
  out[idx] = r;
}

extern "C" void kernel_launch(void* const* d_in, const int* in_sizes, int n_in,
                              void* d_out, int out_size, void* d_ws, size_t ws_size,
                              hipStream_t stream)
{
  const float* x    = (const float*)d_in[0];
  const float* W    = (const float*)d_in[1];
  const float* bias = (const float*)d_in[2];
  const float* E    = (const float*)d_in[3];
  const float* lev  = (const float*)d_in[4];
  const float* lcen = (const float*)d_in[5];
  const float* lh   = (const float*)d_in[6];
  float* out = (float*)d_out;

  char* ws = (char*)d_ws;
  size_t off = 0;
  auto alloc = [&](size_t bytes) -> void* {
    void* p = ws + off;
    off += (bytes + 255) & ~(size_t)255;
    return p;
  };
  unsigned short* phi_bf  = (unsigned short*)alloc((size_t)NB * DE * 2);
  unsigned short* E_bf    = (unsigned short*)alloc((size_t)NEX * DE * 2);
  unsigned short* KM_t    = (unsigned short*)alloc((size_t)ND * NEX * 2);
  float* pn       = (float*)alloc((size_t)NB * 4);
  float* en       = (float*)alloc((size_t)NEX * 4);
  float* baseKM   = (float*)alloc((size_t)ND * 4);
  float* numer_p  = (float*)alloc((size_t)ESPLIT * NB * ND * 4);   // 134 MB
  float* denom_p  = (float*)alloc((size_t)ESPLIT * NB * 4);        // 0.5 MB

  k_encoder<<<NB / 32, 256, 0, stream>>>(x, W, bias, phi_bf, pn);
  k_prep_e<<<NEX / 32, 256, 0, stream>>>(E, E_bf, en);
  k_prep_km<<<NEX / 64, 256, 0, stream>>>(lev, lcen, lh, KM_t, baseKM);
  k_fused<<<dim3(ESPLIT, NB / 128), 256, 0, stream>>>(phi_bf, pn, E_bf, en, KM_t,
                                                      numer_p, denom_p);
  k_finalize<<<(NB * ND) / 256, 256, 0, stream>>>(numer_p, denom_p, baseKM, out);
}

// Round 9
// 189.845 us; speedup vs baseline: 1.6476x; 1.0391x over previous
//
#include <hip/hip_runtime.h>

using short8  = __attribute__((ext_vector_type(8))) short;
using floatx4 = __attribute__((ext_vector_type(4))) float;

#define NB   8192
#define DIN  256
#define DE   128
#define NEX  16384
#define ND   64
#define ESPLIT 16
#define EPB  (NEX/ESPLIT)   // 1024 exemplars per block
#define TE   64
#define NTIL (EPB/TE)       // 16 tiles
#define GAMMA_N 3.6787944117144233e-06f  // exp(-1)/100000

__device__ __forceinline__ unsigned short f2bf(float f) {
  unsigned int u = __float_as_uint(f);
  u += 0x7fffu + ((u >> 16) & 1u);
  return (unsigned short)(u >> 16);
}
__device__ __forceinline__ float bf2f(unsigned short h) {
  return __uint_as_float(((unsigned int)h) << 16);
}
__device__ __forceinline__ unsigned int pk_bf16(float a, float b) {
  unsigned int r;
  asm("v_cvt_pk_bf16_f32 %0, %1, %2" : "=v"(r) : "v"(a), "v"(b));
  return r;
}

__device__ __forceinline__ void gload_lds16(const void* g, void* l) {
  __builtin_amdgcn_global_load_lds(
      (const __attribute__((address_space(1))) void*)g,
      (__attribute__((address_space(3))) void*)l, 16, 0, 0);
}

__device__ __forceinline__ floatx4 mfma_bf16(short8 a, short8 b, floatx4 c) {
  return __builtin_amdgcn_mfma_f32_16x16x32_bf16(a, b, c, 0, 0, 0);
}

// ---------------- fused prep: encoder | E-cast | KM curves ----------------
// Grid-partitioned: blocks [0,1024) encoder (8 rows each, 4 blk/CU),
// [1024,1536) E cast+norm, [1536,2048) KM scans (32 exemplars each).
__global__ __launch_bounds__(256) void k_prep(
    const float* __restrict__ x, const float* __restrict__ W,
    const float* __restrict__ bias, unsigned short* __restrict__ phi_bf,
    float* __restrict__ pn,
    const float* __restrict__ E, unsigned short* __restrict__ E_bf,
    float* __restrict__ en,
    const float* __restrict__ lev, const float* __restrict__ lcen,
    const float* __restrict__ lh, unsigned short* __restrict__ KM_t,
    float* __restrict__ baseKM)
{
  __shared__ __align__(16) unsigned char smem[8192];
  const int bid = blockIdx.x;
  const int tid = threadIdx.x;

  if (bid < 1024) {
    // ---- encoder: 8 rows, thread = 1 row x 4 cols -----------------------
    const int rb = bid * 8;
    float* xs = (float*)smem;                       // [8][256]
    for (int i = tid; i < 8 * DIN / 4; i += 256)
      reinterpret_cast<float4*>(xs)[i] =
          reinterpret_cast<const float4*>(x + (size_t)rb * DIN)[i];
    __syncthreads();
    const int jt = tid & 31;                        // col group j = jt*4
    const int rt = tid >> 5;                        // row 0..7
    float4 acc = *reinterpret_cast<const float4*>(&bias[jt * 4]);
    const float* xr = xs + rt * DIN;
    #pragma unroll 8
    for (int k = 0; k < DIN; ++k) {
      const float4 wv = *reinterpret_cast<const float4*>(&W[k * DE + jt * 4]);
      const float xv = xr[k];                       // 32-lane LDS broadcast
      acc.x = fmaf(xv, wv.x, acc.x); acc.y = fmaf(xv, wv.y, acc.y);
      acc.z = fmaf(xv, wv.z, acc.z); acc.w = fmaf(xv, wv.w, acc.w);
    }
    const int row = rb + rt;
    const unsigned int p0 = pk_bf16(acc.x, acc.y);
    const unsigned int p1 = pk_bf16(acc.z, acc.w);
    *reinterpret_cast<uint2*>(phi_bf + (size_t)row * DE + jt * 4) =
        make_uint2(p0, p1);
    const float h0 = bf2f(p0 & 0xffff), h1 = bf2f(p0 >> 16);
    const float h2 = bf2f(p1 & 0xffff), h3 = bf2f(p1 >> 16);
    float s = h0 * h0 + h1 * h1 + h2 * h2 + h3 * h3;
    s += __shfl_xor(s, 1, 64);
    s += __shfl_xor(s, 2, 64);
    s += __shfl_xor(s, 4, 64);
    s += __shfl_xor(s, 8, 64);
    s += __shfl_xor(s, 16, 64);    // stays within the 32-lane row group
    if (jt == 0) pn[row] = s;

  } else if (bid < 1536) {
    // ---- E cast + |E|^2: 32 rows ----------------------------------------
    const int bb = bid - 1024;
    const int l  = tid & 63;
    const int row = bb * 32 + (tid >> 6) * 8 + (l >> 3);
    const int c0  = (l & 7) * 16;
    const float4* src = reinterpret_cast<const float4*>(E + (size_t)row * DE + c0);
    float4 v0 = src[0], v1 = src[1], v2 = src[2], v3 = src[3];
    unsigned int p[8];
    p[0] = pk_bf16(v0.x, v0.y); p[1] = pk_bf16(v0.z, v0.w);
    p[2] = pk_bf16(v1.x, v1.y); p[3] = pk_bf16(v1.z, v1.w);
    p[4] = pk_bf16(v2.x, v2.y); p[5] = pk_bf16(v2.z, v2.w);
    p[6] = pk_bf16(v3.x, v3.y); p[7] = pk_bf16(v3.z, v3.w);
    uint4* dst = reinterpret_cast<uint4*>(E_bf + (size_t)row * DE + c0);
    dst[0] = make_uint4(p[0], p[1], p[2], p[3]);
    dst[1] = make_uint4(p[4], p[5], p[6], p[7]);
    float s = 0.f;
    #pragma unroll
    for (int i = 0; i < 8; ++i) {
      const float lo = bf2f(p[i] & 0xffff), hi = bf2f(p[i] >> 16);
      s = fmaf(lo, lo, s); s = fmaf(hi, hi, s);
    }
    s += __shfl_xor(s, 1, 64);
    s += __shfl_xor(s, 2, 64);
    s += __shfl_xor(s, 4, 64);
    if ((l & 7) == 0) en[row] = s;

  } else {
    // ---- KM curves -> transposed KM_t[t][e]: 32 exemplars ----------------
    const int bb = bid - 1536;
    unsigned short (*sm)[65] = (unsigned short (*)[65])smem;  // [32][65]
    const int t  = tid & 63;
    const int wv = tid >> 6;
    for (int ee = 0; ee < 8; ++ee) {
      const int el = wv * 8 + ee;
      const int e  = bb * 32 + el;
      const float ev = __expf(lev[e * ND + t]);
      const float cn = __expf(lcen[e * ND + t]);
      float s = ev + cn;
      #pragma unroll
      for (int off = 1; off < 64; off <<= 1) {       // inclusive suffix sum
        const float o = __shfl(s, (t + off) & 63, 64);
        s += (t + off < 64) ? o : 0.0f;
      }
      const float haz = (s > 0.0f) ? (ev / s) : 0.0f;
      float lc = __logf(1.0f - haz + 1e-7f);
      #pragma unroll
      for (int off = 1; off < 64; off <<= 1) {       // inclusive prefix sum
        const float o = __shfl(lc, (t - off) & 63, 64);
        lc += (t >= off) ? o : 0.0f;
      }
      sm[el][t] = f2bf(__expf(lc));
    }
    __syncthreads();
    const int t_out = tid >> 2, prt = tid & 3;       // 64 t x 8 e each
    unsigned short tmp[8];
    #pragma unroll
    for (int i = 0; i < 8; ++i) tmp[i] = sm[prt * 8 + i][t_out];
    *reinterpret_cast<short8*>(KM_t + (size_t)t_out * NEX + bb * 32 + prt * 8) =
        *reinterpret_cast<short8*>(&tmp[0]);
    if (bb == 0 && tid < 64) {
      const float h = 1.0f / (1.0f + __expf(-lh[t]));
      float l2 = __logf(1.0f - h + 1e-7f);
      #pragma unroll
      for (int off = 1; off < 64; off <<= 1) {
        const float o = __shfl(l2, (t - off) & 63, 64);
        l2 += (t >= off) ? o : 0.0f;
      }
      baseKM[t] = __expf(l2);
    }
  }
}

// ---------------- fused (swapped operands, half-tile kw, 32 KB LDS) -------
// GEMM1': C1[e][r] = E . phi^T  -> kw (bf16) to 64B-row LDS, per 32-e half
// GEMM2': C2[t][r] = KM^T . kw^T -> regs; epilogue = f32 floatx4 partials
// (full-line wave stores; coalesced finalize reads).
// launch_bounds (256,4): (256,5) forced VGPR 48 + scratch spills -> 500 MB
// of FETCH/WRITE and 2x slowdown (rounds 6/7). Do not re-tighten.
__global__ __launch_bounds__(256, 4) void k_fused(
    const unsigned short* __restrict__ phi_bf, const float* __restrict__ pn,
    const unsigned short* __restrict__ E_bf, const float* __restrict__ en,
    const unsigned short* __restrict__ KM_t,
    float* __restrict__ numer_p, float* __restrict__ denom_p)
{
  __shared__ __align__(16) unsigned char E_lds[16384];   // [64 e][256B], swizzled
  __shared__ __align__(16) unsigned char KM_lds[8192];   // [64 t][128B], swizzled
  __shared__ __align__(16) unsigned char kw_lds[8192];   // per-wave [32 r][64B], swizzled

  const int tid = threadIdx.x;
  const int w   = tid >> 6;
  const int l   = tid & 63;
  const int lr  = l & 15;
  const int g   = l >> 4;
  const int rowbase = blockIdx.y * 128 + w * 32;
  const int ebase0  = blockIdx.x * EPB;
  const int swz  = (lr & 7) << 4;          // bits 4-6, for 128/256B rows
  const int swz2 = ((lr >> 1) & 3) << 4;   // bits 4-5, for 64B kw rows (b128-safe)

  // persistent B-fragments: phi rows (cols of C), loaded once
  short8 phiB[2][4];
  float  pnf[2];
  #pragma unroll
  for (int n = 0; n < 2; ++n) {
    const int r = rowbase + n * 16 + lr;
    #pragma unroll
    for (int kq = 0; kq < 4; ++kq)
      phiB[n][kq] = *reinterpret_cast<const short8*>(phi_bf + r * DE + kq * 32 + g * 8);
    pnf[n] = pn[r];
  }

  floatx4 c2[4][2];
  #pragma unroll
  for (int m2 = 0; m2 < 4; ++m2)
    #pragma unroll
    for (int n = 0; n < 2; ++n) c2[m2][n] = (floatx4){0.f, 0.f, 0.f, 0.f};
  float dn[2] = {0.f, 0.f};

  for (int it = 0; it < NTIL; ++it) {
    const int ebase = ebase0 + it * TE;
    __syncthreads();                   // prev tile's LDS readers done
    // stage E tile: 16 x 1KB chunks, linear LDS dest, pre-swizzled source
    #pragma unroll
    for (int i = 0; i < 4; ++i) {
      const int c    = w * 4 + i;
      const int row  = c * 4 + (l >> 4);
      const int colB = (l & 15) * 16;
      gload_lds16((const char*)E_bf + (size_t)(ebase + row) * 256 +
                      (colB ^ ((row & 7) << 4)),
                  &E_lds[c * 1024]);
    }
    // stage KM tile: 8 x 1KB chunks from transposed KM_t
    #pragma unroll
    for (int i = 0; i < 2; ++i) {
      const int c    = w * 2 + i;
      const int trow = c * 8 + (l >> 3);
      const int colB = (l & 7) * 16;
      gload_lds16((const char*)KM_t + (size_t)trow * (NEX * 2) + ebase * 2 +
                      (colB ^ ((trow & 7) << 4)),
                  &KM_lds[c * 1024]);
    }
    __syncthreads();

    #pragma unroll
    for (int h = 0; h < 2; ++h) {
      // GEMM1' on this 32-exemplar half + kw pack to LDS
      #pragma unroll
      for (int mm = 0; mm < 2; ++mm) {
        const int m = 2 * h + mm;
        short8 ea[4];
        #pragma unroll
        for (int kq = 0; kq < 4; ++kq)
          ea[kq] = *reinterpret_cast<const short8*>(
              &E_lds[(m * 16 + lr) * 256 + ((kq * 64 + g * 16) ^ swz)]);
        floatx4 c1[2];
        c1[0] = (floatx4){0.f, 0.f, 0.f, 0.f};
        c1[1] = (floatx4){0.f, 0.f, 0.f, 0.f};
        #pragma unroll
        for (int kq = 0; kq < 4; ++kq) {
          c1[0] = mfma_bf16(ea[kq], phiB[0][kq], c1[0]);
          c1[1] = mfma_bf16(ea[kq], phiB[1][kq], c1[1]);
        }
        const floatx4 en4 = *reinterpret_cast<const floatx4*>(&en[ebase + m * 16 + g * 4]);
        #pragma unroll
        for (int n = 0; n < 2; ++n) {
          float kwv[4];
          #pragma unroll
          for (int rg = 0; rg < 4; ++rg) {
            const float d2 = en4[rg] + pnf[n] - 2.0f * c1[n][rg];
            kwv[rg] = (d2 <= 1.0f) ? __expf(-d2) : 0.0f;
            dn[n] += kwv[rg];
          }
          const unsigned int pk0 = pk_bf16(kwv[0], kwv[1]);
          const unsigned int pk1 = pk_bf16(kwv[2], kwv[3]);
          const unsigned long long pk = (unsigned long long)pk0 |
                                        ((unsigned long long)pk1 << 32);
          *reinterpret_cast<unsigned long long*>(
              &kw_lds[w * 2048 + (n * 16 + lr) * 64 + ((mm * 32 + g * 8) ^ swz2)]) = pk;
        }
      }
      // GEMM2' on this half (same-wave LDS RAW, no barrier)
      short8 kwB[2];
      #pragma unroll
      for (int n = 0; n < 2; ++n)
        kwB[n] = *reinterpret_cast<const short8*>(
            &kw_lds[w * 2048 + (n * 16 + lr) * 64 + ((g * 16) ^ swz2)]);
      #pragma unroll
      for (int m2 = 0; m2 < 4; ++m2) {
        const short8 kma = *reinterpret_cast<const short8*>(
            &KM_lds[(m2 * 16 + lr) * 128 + ((h * 64 + g * 16) ^ swz)]);
        c2[m2][0] = mfma_bf16(kma, kwB[0], c2[m2][0]);
        c2[m2][1] = mfma_bf16(kma, kwB[1], c2[m2][1]);
      }
    }
  }

  // epilogue: denom f32 + numer f32 floatx4 stores (full lines, r5-proven)
  #pragma unroll
  for (int n = 0; n < 2; ++n) {
    float v = dn[n];
    v += __shfl_xor(v, 16, 64);
    v += __shfl_xor(v, 32, 64);
    if (l < 16) denom_p[(size_t)blockIdx.x * NB + rowbase + n * 16 + lr] = v;
  }
  float* np = numer_p + ((size_t)blockIdx.x * NB + rowbase) * ND;
  #pragma unroll
  for (int n = 0; n < 2; ++n)
    #pragma unroll
    for (int m2 = 0; m2 < 4; ++m2)
      *reinterpret_cast<floatx4*>(&np[(n * 16 + lr) * ND + m2 * 16 + g * 4]) =
          c2[m2][n];
}

// ---------------- finalize: reduce ESPLIT partials + clip -----------------
__global__ __launch_bounds__(256) void k_finalize(
    const float* __restrict__ numer_p, const float* __restrict__ denom_p,
    const float* __restrict__ baseKM, float* __restrict__ out)
{
  const int idx = blockIdx.x * 256 + threadIdx.x;
  const int b = idx >> 6;
  const int t = idx & 63;
  float num = 0.f, den = 0.f;
  #pragma unroll
  for (int s = 0; s < ESPLIT; ++s) {
    num += numer_p[(size_t)s * NB * ND + idx];
    den += denom_p[(size_t)s * NB + b];
  }
  num += GAMMA_N * baseKM[t];
  den += GAMMA_N + 1e-12f;
  float r = num / den;
  r = fminf(fmaxf(r, 1e-12f), 1.0f - 1e-12f);
  out[idx] = r;
}

extern "C" void kernel_launch(void* const* d_in, const int* in_sizes, int n_in,
                              void* d_out, int out_size, void* d_ws, size_t ws_size,
                              hipStream_t stream)
{
  const float* x    = (const float*)d_in[0];
  const float* W    = (const float*)d_in[1];
  const float* bias = (const float*)d_in[2];
  const float* E    = (const float*)d_in[3];
  const float* lev  = (const float*)d_in[4];
  const float* lcen = (const float*)d_in[5];
  const float* lh   = (const float*)d_in[6];
  float* out = (float*)d_out;

  char* ws = (char*)d_ws;
  size_t off = 0;
  auto alloc = [&](size_t bytes) -> void* {
    void* p = ws + off;
    off += (bytes + 255) & ~(size_t)255;
    return p;
  };
  unsigned short* phi_bf  = (unsigned short*)alloc((size_t)NB * DE * 2);
  unsigned short* E_bf    = (unsigned short*)alloc((size_t)NEX * DE * 2);
  unsigned short* KM_t    = (unsigned short*)alloc((size_t)ND * NEX * 2);
  float* pn       = (float*)alloc((size_t)NB * 4);
  float* en       = (float*)alloc((size_t)NEX * 4);
  float* baseKM   = (float*)alloc((size_t)ND * 4);
  float* numer_p  = (float*)alloc((size_t)ESPLIT * NB * ND * 4);   // 134 MB
  float* denom_p  = (float*)alloc((size_t)ESPLIT * NB * 4);        // 0.5 MB

  k_prep<<<2048, 256, 0, stream>>>(x, W, bias, phi_bf, pn,
                                   E, E_bf, en,
                                   lev, lcen, lh, KM_t, baseKM);
  k_fused<<<dim3(ESPLIT, NB / 128), 256, 0, stream>>>(phi_bf, pn, E_bf, en, KM_t,
                                                      numer_p, denom_p);
  k_finalize<<<(NB * ND) / 256, 256, 0, stream>>>(numer_p, denom_p, baseKM, out);
}

// Round 10
// 184.359 us; speedup vs baseline: 1.6967x; 1.0298x over previous
//
#include <hip/hip_runtime.h>

using short8  = __attribute__((ext_vector_type(8))) short;
using floatx4 = __attribute__((ext_vector_type(4))) float;

#define NB   8192
#define DIN  256
#define DE   128
#define NEX  16384
#define ND   64
#define ESPLIT 32
#define EPB  (NEX/ESPLIT)   // 512 exemplars per block
#define TE   64
#define NTIL (EPB/TE)       // 8 tiles
#define GAMMA_N 3.6787944117144233e-06f  // exp(-1)/100000

__device__ __forceinline__ unsigned short f2bf(float f) {
  unsigned int u = __float_as_uint(f);
  u += 0x7fffu + ((u >> 16) & 1u);
  return (unsigned short)(u >> 16);
}
__device__ __forceinline__ float bf2f(unsigned short h) {
  return __uint_as_float(((unsigned int)h) << 16);
}
__device__ __forceinline__ unsigned int pk_bf16(float a, float b) {
  unsigned int r;
  asm("v_cvt_pk_bf16_f32 %0, %1, %2" : "=v"(r) : "v"(a), "v"(b));
  return r;
}

__device__ __forceinline__ void gload_lds16(const void* g, void* l) {
  __builtin_amdgcn_global_load_lds(
      (const __attribute__((address_space(1))) void*)g,
      (__attribute__((address_space(3))) void*)l, 16, 0, 0);
}

__device__ __forceinline__ floatx4 mfma_bf16(short8 a, short8 b, floatx4 c) {
  return __builtin_amdgcn_mfma_f32_16x16x32_bf16(a, b, c, 0, 0, 0);
}

// ---------------- fused prep: encoder | E-cast | KM curves ----------------
// blocks [0,256): encoder, 32 rows each, 16 rows/thread (W-redundancy 2x ->
//   64 MB W L2 traffic; r9's 8-row blocks caused 1 GB = ~30 us, reverted).
// blocks [256,768): E cast+norm, 32 rows each.
// blocks [768,1280): KM scans, 32 exemplars each.
__global__ __launch_bounds__(256) void k_prep(
    const float* __restrict__ x, const float* __restrict__ W,
    const float* __restrict__ bias, unsigned short* __restrict__ phi_bf,
    float* __restrict__ pn,
    const float* __restrict__ E, unsigned short* __restrict__ E_bf,
    float* __restrict__ en,
    const float* __restrict__ lev, const float* __restrict__ lcen,
    const float* __restrict__ lh, unsigned short* __restrict__ KM_t,
    float* __restrict__ baseKM)
{
  __shared__ float xs[32 * DIN];            // 32 KB (encoder)
  __shared__ float part[32][2];
  __shared__ unsigned short sm[32][65];     // KM transpose staging
  const int bid = blockIdx.x;
  const int tid = threadIdx.x;

  if (bid < 256) {
    // ---- encoder: 32 rows, thread = 16 rows x 1 col ---------------------
    const int rb = bid * 32;
    for (int i = tid; i < 32 * DIN / 4; i += 256)
      reinterpret_cast<float4*>(xs)[i] =
          reinterpret_cast<const float4*>(x + (size_t)rb * DIN)[i];
    __syncthreads();
    const int j  = tid & 127;
    const int rh = tid >> 7;              // 0/1 -> rows rh*16..
    const float bj = bias[j];
    float acc[16];
    #pragma unroll
    for (int r = 0; r < 16; ++r) acc[r] = bj;
    for (int k = 0; k < DIN; ++k) {
      const float wv = W[k * DE + j];
      #pragma unroll
      for (int r = 0; r < 16; ++r)
        acc[r] = fmaf(xs[(rh * 16 + r) * DIN + k], wv, acc[r]);
    }
    const int lane = tid & 63;
    const int jh   = (tid >> 6) & 1;
    #pragma unroll
    for (int r = 0; r < 16; ++r) {
      const int row = rh * 16 + r;
      const unsigned short hb = f2bf(acc[r]);
      phi_bf[(size_t)(rb + row) * DE + j] = hb;
      const float hf = bf2f(hb);
      float sq = hf * hf;
      #pragma unroll
      for (int off = 1; off < 64; off <<= 1) sq += __shfl_xor(sq, off, 64);
      if (lane == 0) part[row][jh] = sq;
    }
    __syncthreads();
    if (tid < 32) pn[rb + tid] = part[tid][0] + part[tid][1];

  } else if (bid < 768) {
    // ---- E cast + |E|^2: 32 rows ----------------------------------------
    const int bb = bid - 256;
    const int l  = tid & 63;
    const int row = bb * 32 + (tid >> 6) * 8 + (l >> 3);
    const int c0  = (l & 7) * 16;
    const float4* src = reinterpret_cast<const float4*>(E + (size_t)row * DE + c0);
    float4 v0 = src[0], v1 = src[1], v2 = src[2], v3 = src[3];
    unsigned int p[8];
    p[0] = pk_bf16(v0.x, v0.y); p[1] = pk_bf16(v0.z, v0.w);
    p[2] = pk_bf16(v1.x, v1.y); p[3] = pk_bf16(v1.z, v1.w);
    p[4] = pk_bf16(v2.x, v2.y); p[5] = pk_bf16(v2.z, v2.w);
    p[6] = pk_bf16(v3.x, v3.y); p[7] = pk_bf16(v3.z, v3.w);
    uint4* dst = reinterpret_cast<uint4*>(E_bf + (size_t)row * DE + c0);
    dst[0] = make_uint4(p[0], p[1], p[2], p[3]);
    dst[1] = make_uint4(p[4], p[5], p[6], p[7]);
    float s = 0.f;
    #pragma unroll
    for (int i = 0; i < 8; ++i) {
      const float lo = bf2f(p[i] & 0xffff), hi = bf2f(p[i] >> 16);
      s = fmaf(lo, lo, s); s = fmaf(hi, hi, s);
    }
    s += __shfl_xor(s, 1, 64);
    s += __shfl_xor(s, 2, 64);
    s += __shfl_xor(s, 4, 64);
    if ((l & 7) == 0) en[row] = s;

  } else {
    // ---- KM curves -> transposed KM_t[t][e]: 32 exemplars ----------------
    const int bb = bid - 768;
    const int t  = tid & 63;
    const int wv = tid >> 6;
    for (int ee = 0; ee < 8; ++ee) {
      const int el = wv * 8 + ee;
      const int e  = bb * 32 + el;
      const float ev = __expf(lev[e * ND + t]);
      const float cn = __expf(lcen[e * ND + t]);
      float s = ev + cn;
      #pragma unroll
      for (int off = 1; off < 64; off <<= 1) {       // inclusive suffix sum
        const float o = __shfl(s, (t + off) & 63, 64);
        s += (t + off < 64) ? o : 0.0f;
      }
      const float haz = (s > 0.0f) ? (ev / s) : 0.0f;
      float lc = __logf(1.0f - haz + 1e-7f);
      #pragma unroll
      for (int off = 1; off < 64; off <<= 1) {       // inclusive prefix sum
        const float o = __shfl(lc, (t - off) & 63, 64);
        lc += (t >= off) ? o : 0.0f;
      }
      sm[el][t] = f2bf(__expf(lc));
    }
    __syncthreads();
    const int t_out = tid >> 2, prt = tid & 3;       // 64 t x 8 e each
    unsigned short tmp[8];
    #pragma unroll
    for (int i = 0; i < 8; ++i) tmp[i] = sm[prt * 8 + i][t_out];
    *reinterpret_cast<short8*>(KM_t + (size_t)t_out * NEX + bb * 32 + prt * 8) =
        *reinterpret_cast<short8*>(&tmp[0]);
    if (bb == 0 && tid < 64) {
      const float h = 1.0f / (1.0f + __expf(-lh[t]));
      float l2 = __logf(1.0f - h + 1e-7f);
      #pragma unroll
      for (int off = 1; off < 64; off <<= 1) {
        const float o = __shfl(l2, (t - off) & 63, 64);
        l2 += (t >= off) ? o : 0.0f;
      }
      baseKM[t] = __expf(l2);
    }
  }
}

// ---------------- fused (swapped operands, half-tile kw, 32 KB LDS) -------
// GEMM1': C1[e][r] = E . phi^T  -> kw (bf16) to 64B-row LDS, per 32-e half
// GEMM2': C2[t][r] = KM^T . kw^T -> regs.
// Epilogue: bf16 partials, m2-PAIRED uint4 stores = 64B full lines per row
// (r6's 32B half-line uint2 stores caused RFO; r6 precision was FINE).
// launch_bounds (256,4): (256,5) forced VGPR 48 + scratch spills -> 500 MB
// of FETCH/WRITE and 2x slowdown (rounds 6/7). Do not re-tighten.
__global__ __launch_bounds__(256, 4) void k_fused(
    const unsigned short* __restrict__ phi_bf, const float* __restrict__ pn,
    const unsigned short* __restrict__ E_bf, const float* __restrict__ en,
    const unsigned short* __restrict__ KM_t,
    uint4* __restrict__ numer_p, float* __restrict__ denom_p)
{
  __shared__ __align__(16) unsigned char E_lds[16384];   // [64 e][256B], swizzled
  __shared__ __align__(16) unsigned char KM_lds[8192];   // [64 t][128B], swizzled
  __shared__ __align__(16) unsigned char kw_lds[8192];   // per-wave [32 r][64B], swizzled

  const int tid = threadIdx.x;
  const int w   = tid >> 6;
  const int l   = tid & 63;
  const int lr  = l & 15;
  const int g   = l >> 4;
  const int rowbase = blockIdx.y * 128 + w * 32;
  const int ebase0  = blockIdx.x * EPB;
  const int swz  = (lr & 7) << 4;          // bits 4-6, for 128/256B rows
  const int swz2 = ((lr >> 1) & 3) << 4;   // bits 4-5, for 64B kw rows (b128-safe)

  // persistent B-fragments: phi rows (cols of C), loaded once
  short8 phiB[2][4];
  float  pnf[2];
  #pragma unroll
  for (int n = 0; n < 2; ++n) {
    const int r = rowbase + n * 16 + lr;
    #pragma unroll
    for (int kq = 0; kq < 4; ++kq)
      phiB[n][kq] = *reinterpret_cast<const short8*>(phi_bf + r * DE + kq * 32 + g * 8);
    pnf[n] = pn[r];
  }

  floatx4 c2[4][2];
  #pragma unroll
  for (int m2 = 0; m2 < 4; ++m2)
    #pragma unroll
    for (int n = 0; n < 2; ++n) c2[m2][n] = (floatx4){0.f, 0.f, 0.f, 0.f};
  float dn[2] = {0.f, 0.f};

  for (int it = 0; it < NTIL; ++it) {
    const int ebase = ebase0 + it * TE;
    __syncthreads();                   // prev tile's LDS readers done
    // stage E tile: 16 x 1KB chunks, linear LDS dest, pre-swizzled source
    #pragma unroll
    for (int i = 0; i < 4; ++i) {
      const int c    = w * 4 + i;
      const int row  = c * 4 + (l >> 4);
      const int colB = (l & 15) * 16;
      gload_lds16((const char*)E_bf + (size_t)(ebase + row) * 256 +
                      (colB ^ ((row & 7) << 4)),
                  &E_lds[c * 1024]);
    }
    // stage KM tile: 8 x 1KB chunks from transposed KM_t
    #pragma unroll
    for (int i = 0; i < 2; ++i) {
      const int c    = w * 2 + i;
      const int trow = c * 8 + (l >> 3);
      const int colB = (l & 7) * 16;
      gload_lds16((const char*)KM_t + (size_t)trow * (NEX * 2) + ebase * 2 +
                      (colB ^ ((trow & 7) << 4)),
                  &KM_lds[c * 1024]);
    }
    __syncthreads();

    #pragma unroll
    for (int h = 0; h < 2; ++h) {
      // GEMM1' on this 32-exemplar half + kw pack to LDS
      #pragma unroll
      for (int mm = 0; mm < 2; ++mm) {
        const int m = 2 * h + mm;
        short8 ea[4];
        #pragma unroll
        for (int kq = 0; kq < 4; ++kq)
          ea[kq] = *reinterpret_cast<const short8*>(
              &E_lds[(m * 16 + lr) * 256 + ((kq * 64 + g * 16) ^ swz)]);
        floatx4 c1[2];
        c1[0] = (floatx4){0.f, 0.f, 0.f, 0.f};
        c1[1] = (floatx4){0.f, 0.f, 0.f, 0.f};
        #pragma unroll
        for (int kq = 0; kq < 4; ++kq) {
          c1[0] = mfma_bf16(ea[kq], phiB[0][kq], c1[0]);
          c1[1] = mfma_bf16(ea[kq], phiB[1][kq], c1[1]);
        }
        const floatx4 en4 = *reinterpret_cast<const floatx4*>(&en[ebase + m * 16 + g * 4]);
        #pragma unroll
        for (int n = 0; n < 2; ++n) {
          float kwv[4];
          #pragma unroll
          for (int rg = 0; rg < 4; ++rg) {
            const float d2 = en4[rg] + pnf[n] - 2.0f * c1[n][rg];
            kwv[rg] = (d2 <= 1.0f) ? __expf(-d2) : 0.0f;
            dn[n] += kwv[rg];
          }
          const unsigned int pk0 = pk_bf16(kwv[0], kwv[1]);
          const unsigned int pk1 = pk_bf16(kwv[2], kwv[3]);
          const unsigned long long pk = (unsigned long long)pk0 |
                                        ((unsigned long long)pk1 << 32);
          *reinterpret_cast<unsigned long long*>(
              &kw_lds[w * 2048 + (n * 16 + lr) * 64 + ((mm * 32 + g * 8) ^ swz2)]) = pk;
        }
      }
      // GEMM2' on this half (same-wave LDS RAW, no barrier)
      short8 kwB[2];
      #pragma unroll
      for (int n = 0; n < 2; ++n)
        kwB[n] = *reinterpret_cast<const short8*>(
            &kw_lds[w * 2048 + (n * 16 + lr) * 64 + ((g * 16) ^ swz2)]);
      #pragma unroll
      for (int m2 = 0; m2 < 4; ++m2) {
        const short8 kma = *reinterpret_cast<const short8*>(
            &KM_lds[(m2 * 16 + lr) * 128 + ((h * 64 + g * 16) ^ swz)]);
        c2[m2][0] = mfma_bf16(kma, kwB[0], c2[m2][0]);
        c2[m2][1] = mfma_bf16(kma, kwB[1], c2[m2][1]);
      }
    }
  }

  // epilogue: denom f32 + numer bf16, m2-paired uint4 (64B/row full lines)
  // row byte layout: pos(t) = p*32 + g*8 + mm*4 + rg, m2 = 2p+mm
  #pragma unroll
  for (int n = 0; n < 2; ++n) {
    float v = dn[n];
    v += __shfl_xor(v, 16, 64);
    v += __shfl_xor(v, 32, 64);
    if (l < 16) denom_p[(size_t)blockIdx.x * NB + rowbase + n * 16 + lr] = v;
  }
  #pragma unroll
  for (int n = 0; n < 2; ++n) {
    const size_t rbase = ((size_t)blockIdx.x * NB + rowbase + n * 16 + lr) * 8;
    #pragma unroll
    for (int p = 0; p < 2; ++p)
      numer_p[rbase + p * 4 + g] =
          make_uint4(pk_bf16(c2[2 * p][n][0],     c2[2 * p][n][1]),
                     pk_bf16(c2[2 * p][n][2],     c2[2 * p][n][3]),
                     pk_bf16(c2[2 * p + 1][n][0], c2[2 * p + 1][n][1]),
                     pk_bf16(c2[2 * p + 1][n][2], c2[2 * p + 1][n][3]));
  }
}

// ---------------- finalize: reduce ESPLIT bf16 partials + clip ------------
__global__ __launch_bounds__(256) void k_finalize(
    const unsigned short* __restrict__ numer_p, const float* __restrict__ denom_p,
    const float* __restrict__ baseKM, float* __restrict__ out)
{
  const int idx = blockIdx.x * 256 + threadIdx.x;
  const int b = idx >> 6;
  const int t = idx & 63;
  // invert k_fused's paired store layout
  const int m2 = t >> 4, g = (t >> 2) & 3, rg = t & 3;
  const int pos = (m2 >> 1) * 32 + g * 8 + (m2 & 1) * 4 + rg;
  float num = 0.f, den = 0.f;
  #pragma unroll
  for (int s = 0; s < ESPLIT; ++s) {
    num += bf2f(numer_p[(size_t)s * NB * ND + (size_t)b * ND + pos]);
    den += denom_p[(size_t)s * NB + b];
  }
  num += GAMMA_N * baseKM[t];
  den += GAMMA_N + 1e-12f;
  float r = num / den;
  r = fminf(fmaxf(r, 1e-12f), 1.0f - 1e-12f);
  out[idx] = r;
}

extern "C" void kernel_launch(void* const* d_in, const int* in_sizes, int n_in,
                              void* d_out, int out_size, void* d_ws, size_t ws_size,
                              hipStream_t stream)
{
  const float* x    = (const float*)d_in[0];
  const float* W    = (const float*)d_in[1];
  const float* bias = (const float*)d_in[2];
  const float* E    = (const float*)d_in[3];
  const float* lev  = (const float*)d_in[4];
  const float* lcen = (const float*)d_in[5];
  const float* lh   = (const float*)d_in[6];
  float* out = (float*)d_out;

  char* ws = (char*)d_ws;
  size_t off = 0;
  auto alloc = [&](size_t bytes) -> void* {
    void* p = ws + off;
    off += (bytes + 255) & ~(size_t)255;
    return p;
  };
  unsigned short* phi_bf  = (unsigned short*)alloc((size_t)NB * DE * 2);
  unsigned short* E_bf    = (unsigned short*)alloc((size_t)NEX * DE * 2);
  unsigned short* KM_t    = (unsigned short*)alloc((size_t)ND * NEX * 2);
  float* pn       = (float*)alloc((size_t)NB * 4);
  float* en       = (float*)alloc((size_t)NEX * 4);
  float* baseKM   = (float*)alloc((size_t)ND * 4);
  uint4* numer_p  = (uint4*)alloc((size_t)ESPLIT * NB * ND * 2);   // 33.5 MB
  float* denom_p  = (float*)alloc((size_t)ESPLIT * NB * 4);        // 1 MB

  k_prep<<<1280, 256, 0, stream>>>(x, W, bias, phi_bf, pn,
                                   E, E_bf, en,
                                   lev, lcen, lh, KM_t, baseKM);
  k_fused<<<dim3(ESPLIT, NB / 128), 256, 0, stream>>>(phi_bf, pn, E_bf, en, KM_t,
                                                      numer_p, denom_p);
  k_finalize<<<(NB * ND) / 256, 256, 0, stream>>>((const unsigned short*)numer_p,
                                                  denom_p, baseKM, out);
}